// Round 1
// baseline (623.966 us; speedup 1.0000x reference)
//
#include <hip/hip_runtime.h>
#include <hip/hip_bf16.h>

#define N_NODES 100000
#define N_EDGES 640000
#define DIM 128
#define NE_TOT (N_NODES + N_EDGES)

// ---------------- graph prep ----------------

__global__ void init_deg_kernel(int* deg, int n) {
    int i = blockIdx.x * blockDim.x + threadIdx.x;
    if (i < n) deg[i] = 1;  // self-loop
}

__global__ void count_deg_kernel(const int* __restrict__ edges, int* deg, int e) {
    int i = blockIdx.x * blockDim.x + threadIdx.x;
    if (i < e) atomicAdd(&deg[edges[N_EDGES + i]], 1);  // dst row
}

// block scans 1024 elements (256 thr x 4)
__global__ void scan1_kernel(const int* __restrict__ deg, int* off, int* bsums, int n) {
    __shared__ int lds[256];
    int t = threadIdx.x;
    int base = blockIdx.x * 1024 + t * 4;
    int v[4]; int s = 0;
#pragma unroll
    for (int j = 0; j < 4; j++) { int idx = base + j; v[j] = (idx < n) ? deg[idx] : 0; s += v[j]; }
    lds[t] = s; __syncthreads();
    for (int d = 1; d < 256; d <<= 1) {
        int x = 0;
        if (t >= d) x = lds[t - d];
        __syncthreads();
        if (t >= d) lds[t] += x;
        __syncthreads();
    }
    if (t == 255) bsums[blockIdx.x] = lds[255];
    int run = lds[t] - s;  // exclusive prefix of this thread's chunk
#pragma unroll
    for (int j = 0; j < 4; j++) { int idx = base + j; if (idx < n) off[idx] = run; run += v[j]; }
}

__global__ void scan2_kernel(int* bsums, int nchunks) {
    __shared__ int lds[128];
    int t = threadIdx.x;
    int v = (t < nchunks) ? bsums[t] : 0;
    lds[t] = v; __syncthreads();
    for (int d = 1; d < 128; d <<= 1) {
        int x = 0;
        if (t >= d) x = lds[t - d];
        __syncthreads();
        if (t >= d) lds[t] += x;
        __syncthreads();
    }
    if (t < nchunks) bsums[t] = lds[t] - v;  // exclusive
}

__global__ void scan3_kernel(int* off, const int* __restrict__ bsums, const int* __restrict__ deg,
                             int* cursor, float* dinv, int n) {
    int i = blockIdx.x * blockDim.x + threadIdx.x;
    if (i < n) {
        int o = off[i] + bsums[i >> 10];
        off[i] = o;
        cursor[i] = o;
        dinv[i] = 1.0f / sqrtf((float)deg[i]);
    }
}

__global__ void fill_csr_kernel(const int* __restrict__ edges, int* cursor, int* csr) {
    int i = blockIdx.x * blockDim.x + threadIdx.x;
    if (i < N_NODES) {
        int p = atomicAdd(&cursor[i], 1);
        csr[p] = i;                      // self loop
    } else if (i < NE_TOT) {
        int e = i - N_NODES;
        int s = edges[e];                // src row
        int d = edges[N_EDGES + e];      // dst row
        int p = atomicAdd(&cursor[d], 1);
        csr[p] = s;
    }
}

// ---------------- aggregation: y[i] = dinv[i] * sum_{s in nbrs(i)} x[s]*dinv[s] ----------------
// one wave per node, lane covers 2 dims (float2)
__global__ void aggregate_kernel(const float* __restrict__ x, float* __restrict__ y,
                                 const int* __restrict__ off, const int* __restrict__ csr,
                                 const float* __restrict__ dinv, int n) {
    int wid = (blockIdx.x * blockDim.x + threadIdx.x) >> 6;
    int lane = threadIdx.x & 63;
    if (wid >= n) return;
    int start = off[wid];
    int end = (wid == n - 1) ? NE_TOT : off[wid + 1];
    int d0 = lane * 2;
    float ax = 0.f, ay = 0.f;
    for (int k = start; k < end; k++) {
        int s = csr[k];
        float w = dinv[s];
        float2 xv = *reinterpret_cast<const float2*>(x + (size_t)s * DIM + d0);
        ax += xv.x * w;
        ay += xv.y * w;
    }
    float di = dinv[wid];
    float2 o; o.x = ax * di; o.y = ay * di;
    *reinterpret_cast<float2*>(y + (size_t)wid * DIM + d0) = o;
}

// ---------------- GEMM: out = relu(A @ W + b), A:[M,128], W:[128,128] ----------------
// block: 256 thr, tile 64 rows x 64 cols (blockIdx.y = col half), 4x4 per thread
__global__ __launch_bounds__(256, 2) void gemm_bias_relu_kernel(
        const float* __restrict__ A, const float* __restrict__ W,
        const float* __restrict__ bias, float* __restrict__ out, int M) {
    __shared__ float Xs[64][132];   // +4 pad: rows on different banks
    __shared__ float Ws[128][64];
    const int t = threadIdx.x;
    const int cb = blockIdx.y;           // 0 or 1
    const int rowbase = blockIdx.x * 64;

    // stage W half: W[k][cb*64 + c], 128x64 floats = 2048 float4
    for (int i = t; i < 2048; i += 256) {
        int k = i >> 4, c4 = i & 15;
        float4 v = *reinterpret_cast<const float4*>(W + k * DIM + cb * 64 + c4 * 4);
        *reinterpret_cast<float4*>(&Ws[k][c4 * 4]) = v;
    }
    // stage X tile: 64x128 floats = 2048 float4
    for (int i = t; i < 2048; i += 256) {
        int r = i >> 5, c4 = i & 31;
        int row = rowbase + r;
        float4 v = make_float4(0.f, 0.f, 0.f, 0.f);
        if (row < M) v = *reinterpret_cast<const float4*>(A + (size_t)row * DIM + c4 * 4);
        *reinterpret_cast<float4*>(&Xs[r][c4 * 4]) = v;
    }
    __syncthreads();

    const int tx = t & 15, ty = t >> 4;  // 16x16 threads, each 4 rows x 4 cols
    float acc[4][4];
#pragma unroll
    for (int r = 0; r < 4; r++)
#pragma unroll
        for (int c = 0; c < 4; c++) acc[r][c] = 0.f;

    for (int k = 0; k < 128; k += 4) {
        float4 a[4];
#pragma unroll
        for (int r = 0; r < 4; r++) a[r] = *reinterpret_cast<float4*>(&Xs[ty * 4 + r][k]);
#pragma unroll
        for (int kk = 0; kk < 4; kk++) {
            float4 wv = *reinterpret_cast<float4*>(&Ws[k + kk][tx * 4]);
#pragma unroll
            for (int r = 0; r < 4; r++) {
                float av = (&a[r].x)[kk];
                acc[r][0] += av * wv.x;
                acc[r][1] += av * wv.y;
                acc[r][2] += av * wv.z;
                acc[r][3] += av * wv.w;
            }
        }
    }

    float bc[4];
#pragma unroll
    for (int c = 0; c < 4; c++) bc[c] = bias[cb * 64 + tx * 4 + c];
#pragma unroll
    for (int r = 0; r < 4; r++) {
        int row = rowbase + ty * 4 + r;
        if (row < M) {
            float4 o;
            o.x = fmaxf(acc[r][0] + bc[0], 0.f);
            o.y = fmaxf(acc[r][1] + bc[1], 0.f);
            o.z = fmaxf(acc[r][2] + bc[2], 0.f);
            o.w = fmaxf(acc[r][3] + bc[3], 0.f);
            *reinterpret_cast<float4*>(out + (size_t)row * DIM + cb * 64 + tx * 4) = o;
        }
    }
}

// ---------------- classifier: out[i][0..1] = x[i] . clfW[:,j] + clfb ----------------
__global__ void classifier_kernel(const float* __restrict__ x, const float* __restrict__ clfW,
                                  const float* __restrict__ clfb, float* __restrict__ out, int n) {
    int wid = (blockIdx.x * blockDim.x + threadIdx.x) >> 6;
    int lane = threadIdx.x & 63;
    if (wid >= n) return;
    float w00 = clfW[2 * lane], w01 = clfW[2 * lane + 1];
    float w10 = clfW[2 * (lane + 64)], w11 = clfW[2 * (lane + 64) + 1];
    float x0 = x[(size_t)wid * DIM + lane];
    float x1 = x[(size_t)wid * DIM + lane + 64];
    float a0 = x0 * w00 + x1 * w10;
    float a1 = x0 * w01 + x1 * w11;
#pragma unroll
    for (int d = 32; d > 0; d >>= 1) {
        a0 += __shfl_down(a0, d);
        a1 += __shfl_down(a1, d);
    }
    if (lane == 0) {
        out[2 * wid]     = a0 + clfb[0];
        out[2 * wid + 1] = a1 + clfb[1];
    }
}

extern "C" void kernel_launch(void* const* d_in, const int* in_sizes, int n_in,
                              void* d_out, int out_size, void* d_ws, size_t ws_size,
                              hipStream_t stream) {
    const float* nodes = (const float*)d_in[0];
    const int*   edges = (const int*)d_in[1];
    const float* W     = (const float*)d_in[2];
    const float* b     = (const float*)d_in[3];
    const float* clfW  = (const float*)d_in[4];
    const float* clfb  = (const float*)d_in[5];
    float* out = (float*)d_out;

    const int N = N_NODES, E = N_EDGES;

    // workspace layout
    float* X    = (float*)d_ws;          // N*DIM
    float* Y    = X + (size_t)N * DIM;   // N*DIM
    float* dinv = Y + (size_t)N * DIM;   // N
    int* deg    = (int*)(dinv + N);      // N
    int* off    = deg + N;               // N
    int* cursor = off + N;               // N
    int* csr    = cursor + N;            // N+E
    int* bsums  = csr + NE_TOT;          // 128

    const int nchunks = (N + 1023) / 1024;  // 98

    init_deg_kernel<<<(N + 255) / 256, 256, 0, stream>>>(deg, N);
    count_deg_kernel<<<(E + 255) / 256, 256, 0, stream>>>(edges, deg, E);
    scan1_kernel<<<nchunks, 256, 0, stream>>>(deg, off, bsums, N);
    scan2_kernel<<<1, 128, 0, stream>>>(bsums, nchunks);
    scan3_kernel<<<(N + 255) / 256, 256, 0, stream>>>(off, bsums, deg, cursor, dinv, N);
    fill_csr_kernel<<<(NE_TOT + 255) / 256, 256, 0, stream>>>(edges, cursor, csr);

    const int aggBlocks = (N + 3) / 4;            // 1 wave/node, 4 waves/block
    dim3 gemmGrid((N + 63) / 64, 2);

    // layer 0: aggregate(nodes)->Y, gemm(Y, W0)->X
    aggregate_kernel<<<aggBlocks, 256, 0, stream>>>(nodes, Y, off, csr, dinv, N);
    gemm_bias_relu_kernel<<<gemmGrid, 256, 0, stream>>>(Y, W, b, X, N);
    // layer 1
    aggregate_kernel<<<aggBlocks, 256, 0, stream>>>(X, Y, off, csr, dinv, N);
    gemm_bias_relu_kernel<<<gemmGrid, 256, 0, stream>>>(Y, W + DIM * DIM, b + DIM, X, N);
    // layer 2
    aggregate_kernel<<<aggBlocks, 256, 0, stream>>>(X, Y, off, csr, dinv, N);
    gemm_bias_relu_kernel<<<gemmGrid, 256, 0, stream>>>(Y, W + 2 * DIM * DIM, b + 2 * DIM, X, N);
    // classifier
    classifier_kernel<<<aggBlocks, 256, 0, stream>>>(X, clfW, clfb, out, N);
}

// Round 6
// 558.353 us; speedup vs baseline: 1.1175x; 1.1175x over previous
//
#include <hip/hip_runtime.h>
#include <hip/hip_bf16.h>

#define N_NODES 100000
#define N_EDGES 640000
#define DIM 128
#define NE_TOT (N_NODES + N_EDGES)

typedef unsigned short u16;
typedef unsigned int u32;
typedef __attribute__((ext_vector_type(8))) short bf16x8;   // 8 bf16 bit-patterns (guide §3 convention)
typedef __attribute__((ext_vector_type(4))) float f32x4;
typedef __attribute__((ext_vector_type(8))) unsigned short us8;

__device__ __forceinline__ u16 f2bf(float f) {
    u32 u = __float_as_uint(f);
    u32 r = (u + 0x7fffu + ((u >> 16) & 1u)) >> 16;   // RNE
    return (u16)r;
}
__device__ __forceinline__ float bf2f(u16 h) { return __uint_as_float(((u32)h) << 16); }

__device__ __forceinline__ void gload16(const void* g, void* l) {
    __builtin_amdgcn_global_load_lds(
        (const __attribute__((address_space(1))) u32*)g,
        (__attribute__((address_space(3))) u32*)l, 16, 0, 0);
}

// ---------------- graph prep ----------------

__global__ void init_deg_kernel(int* deg, int n) {
    int i = blockIdx.x * blockDim.x + threadIdx.x;
    if (i < n) deg[i] = 1;  // self-loop
}

__global__ void count_deg_kernel(const int* __restrict__ edges, int* deg, int e) {
    int i = blockIdx.x * blockDim.x + threadIdx.x;
    if (i < e) atomicAdd(&deg[edges[N_EDGES + i]], 1);  // dst row
}

__global__ void scan1_kernel(const int* __restrict__ deg, int* off, int* bsums, int n) {
    __shared__ int lds[256];
    int t = threadIdx.x;
    int base = blockIdx.x * 1024 + t * 4;
    int v[4]; int s = 0;
#pragma unroll
    for (int j = 0; j < 4; j++) { int idx = base + j; v[j] = (idx < n) ? deg[idx] : 0; s += v[j]; }
    lds[t] = s; __syncthreads();
    for (int d = 1; d < 256; d <<= 1) {
        int x = 0;
        if (t >= d) x = lds[t - d];
        __syncthreads();
        if (t >= d) lds[t] += x;
        __syncthreads();
    }
    if (t == 255) bsums[blockIdx.x] = lds[255];
    int run = lds[t] - s;
#pragma unroll
    for (int j = 0; j < 4; j++) { int idx = base + j; if (idx < n) off[idx] = run; run += v[j]; }
}

__global__ void scan2_kernel(int* bsums, int nchunks) {
    __shared__ int lds[128];
    int t = threadIdx.x;
    int v = (t < nchunks) ? bsums[t] : 0;
    lds[t] = v; __syncthreads();
    for (int d = 1; d < 128; d <<= 1) {
        int x = 0;
        if (t >= d) x = lds[t - d];
        __syncthreads();
        if (t >= d) lds[t] += x;
        __syncthreads();
    }
    if (t < nchunks) bsums[t] = lds[t] - v;
}

__global__ void scan3_kernel(int* off, const int* __restrict__ bsums, const int* __restrict__ deg,
                             int* cursor, float* dinv, int n) {
    int i = blockIdx.x * blockDim.x + threadIdx.x;
    if (i < n) {
        int o = off[i] + bsums[i >> 10];
        off[i] = o;
        cursor[i] = o;
        dinv[i] = 1.0f / sqrtf((float)deg[i]);
    }
}

__global__ void fill_csr_kernel(const int* __restrict__ edges, int* cursor, int* csr) {
    int i = blockIdx.x * blockDim.x + threadIdx.x;
    if (i < N_NODES) {
        int p = atomicAdd(&cursor[i], 1);
        csr[p] = i;
    } else if (i < NE_TOT) {
        int e = i - N_NODES;
        int s = edges[e];
        int d = edges[N_EDGES + e];
        int p = atomicAdd(&cursor[d], 1);
        csr[p] = s;
    }
}

// ---------------- W prep: split fp32 W -> bf16 hi/lo, transposed [col][k], pre-swizzled ----------------
__global__ void wsplit_kernel(const float* __restrict__ W, u16* __restrict__ WhiT, u16* __restrict__ WloT) {
    int i = blockIdx.x * 256 + threadIdx.x;       // 0 .. 3*128*128-1
    int l = i >> 14; int r = i & 16383; int k = r >> 7; int c = r & 127;
    float w = W[i];                                // W[l][k][c]
    u16 h = f2bf(w);
    u16 lo = f2bf(w - bf2f(h));
    u32 inner = ((u32)(k * 2)) ^ (((u32)c & 7u) << 4);   // swizzled byte within 256B row
    size_t db = (size_t)l * 32768 + (size_t)c * 256 + inner;
    *(u16*)((char*)WhiT + db) = h;
    *(u16*)((char*)WloT + db) = lo;
}

// ---------------- aggregation: writes swizzled split-bf16 ----------------
__global__ void aggregate_kernel(const float* __restrict__ x, u16* __restrict__ yhi, u16* __restrict__ ylo,
                                 const int* __restrict__ off, const int* __restrict__ csr,
                                 const float* __restrict__ dinv, int n) {
    int wid = (blockIdx.x * blockDim.x + threadIdx.x) >> 6;
    int lane = threadIdx.x & 63;
    if (wid >= n) return;
    int start = off[wid];
    int end = (wid == n - 1) ? NE_TOT : off[wid + 1];
    int d0 = lane * 2;
    float ax = 0.f, ay = 0.f;
    for (int k = start; k < end; k++) {
        int s = csr[k];
        float w = dinv[s];
        float2 xv = *reinterpret_cast<const float2*>(x + (size_t)s * DIM + d0);
        ax += xv.x * w;
        ay += xv.y * w;
    }
    float di = dinv[wid];
    float vx = ax * di, vy = ay * di;
    u16 hx = f2bf(vx); u16 lx = f2bf(vx - bf2f(hx));
    u16 hy = f2bf(vy); u16 ly = f2bf(vy - bf2f(hy));
    u32 inner = ((u32)(lane * 4)) ^ (((u32)wid & 7u) << 4);   // pre-swizzled store
    *(u32*)((char*)yhi + (size_t)wid * 256 + inner) = (u32)hx | ((u32)hy << 16);
    *(u32*)((char*)ylo + (size_t)wid * 256 + inner) = (u32)lx | ((u32)ly << 16);
}

// ---------------- split-bf16 MFMA GEMM: out = relu(Y @ W + b) ----------------
// block: 512 thr (8 waves = 4 row x 2 col), tile 128 rows x 128 cols, K=128 unrolled.
// LDS 128KB: Ah/Al [128][128] bf16 swizzled, Bh/Bl = W^T [col][k] bf16 swizzled.
// 3-product split GEMM: hi*hi + hi*lo + lo*hi (lo*lo term < 2^-18 rel, dropped).
__device__ __forceinline__ bf16x8 lds_frag(const char* base, int row, int kbyte) {
    int off = row * 256 + (kbyte ^ ((row & 7) << 4));
    return __builtin_bit_cast(bf16x8, *(const us8*)(base + off));
}

__global__ __launch_bounds__(512, 1) void gemm_mfma_kernel(
        const u16* __restrict__ Yhi, const u16* __restrict__ Ylo,
        const u16* __restrict__ WhiT, const u16* __restrict__ WloT,
        const float* __restrict__ bias, float* __restrict__ out, int M) {
    __shared__ char smem[131072];
    char* Ah = smem;
    char* Al = smem + 32768;
    char* Bh = smem + 65536;
    char* Bl = smem + 98304;
    const int t = threadIdx.x;
    const int lane = t & 63, w = t >> 6;
    const int rowbase = blockIdx.x * 128;

    // stage: each wave copies its 16-row slice of all 4 arrays (linear dest, src already swizzled)
#pragma unroll
    for (int it = 0; it < 4; it++) {
        int p = w * 4096 + it * 1024 + lane * 16;   // byte within 32KB tile
        int rl = p >> 8;
        int rg = rowbase + rl; rg = (rg < M) ? rg : (M - 1);
        int inner = p & 255;
        gload16((const char*)Yhi + (size_t)rg * 256 + inner, Ah + w * 4096 + it * 1024);
        gload16((const char*)Ylo + (size_t)rg * 256 + inner, Al + w * 4096 + it * 1024);
        gload16((const char*)WhiT + p, Bh + w * 4096 + it * 1024);
        gload16((const char*)WloT + p, Bl + w * 4096 + it * 1024);
    }
    __syncthreads();

    const int wr = w >> 1, wc = w & 1;
    const int lr = lane & 15, kh = lane >> 4;
    f32x4 acc[2][4] = {};

#pragma unroll
    for (int ks = 0; ks < 4; ks++) {
        int kb = ks * 64 + kh * 16;
        bf16x8 ah[2], al[2], bh[4], bl[4];
#pragma unroll
        for (int ri = 0; ri < 2; ri++) {
            ah[ri] = lds_frag(Ah, wr * 32 + ri * 16 + lr, kb);
            al[ri] = lds_frag(Al, wr * 32 + ri * 16 + lr, kb);
        }
#pragma unroll
        for (int ci = 0; ci < 4; ci++) {
            bh[ci] = lds_frag(Bh, wc * 64 + ci * 16 + lr, kb);
            bl[ci] = lds_frag(Bl, wc * 64 + ci * 16 + lr, kb);
        }
#pragma unroll
        for (int ri = 0; ri < 2; ri++)
#pragma unroll
            for (int ci = 0; ci < 4; ci++) {
                acc[ri][ci] = __builtin_amdgcn_mfma_f32_16x16x32_bf16(ah[ri], bh[ci], acc[ri][ci], 0, 0, 0);
                acc[ri][ci] = __builtin_amdgcn_mfma_f32_16x16x32_bf16(ah[ri], bl[ci], acc[ri][ci], 0, 0, 0);
                acc[ri][ci] = __builtin_amdgcn_mfma_f32_16x16x32_bf16(al[ri], bh[ci], acc[ri][ci], 0, 0, 0);
            }
    }

    // epilogue: C/D layout col=lane&15, row=(lane>>4)*4+reg  [m89-verified]
#pragma unroll
    for (int ri = 0; ri < 2; ri++)
#pragma unroll
        for (int ci = 0; ci < 4; ci++) {
            int col = wc * 64 + ci * 16 + lr;
            float bc = bias[col];
            int r0 = rowbase + wr * 32 + ri * 16 + kh * 4;
#pragma unroll
            for (int j = 0; j < 4; j++) {
                int r = r0 + j;
                if (r < M) out[(size_t)r * 128 + col] = fmaxf(acc[ri][ci][j] + bc, 0.f);
            }
        }
}

// ---------------- classifier ----------------
__global__ void classifier_kernel(const float* __restrict__ x, const float* __restrict__ clfW,
                                  const float* __restrict__ clfb, float* __restrict__ out, int n) {
    int wid = (blockIdx.x * blockDim.x + threadIdx.x) >> 6;
    int lane = threadIdx.x & 63;
    if (wid >= n) return;
    float w00 = clfW[2 * lane], w01 = clfW[2 * lane + 1];
    float w10 = clfW[2 * (lane + 64)], w11 = clfW[2 * (lane + 64) + 1];
    float x0 = x[(size_t)wid * DIM + lane];
    float x1 = x[(size_t)wid * DIM + lane + 64];
    float a0 = x0 * w00 + x1 * w10;
    float a1 = x0 * w01 + x1 * w11;
#pragma unroll
    for (int d = 32; d > 0; d >>= 1) {
        a0 += __shfl_down(a0, d);
        a1 += __shfl_down(a1, d);
    }
    if (lane == 0) {
        out[2 * wid]     = a0 + clfb[0];
        out[2 * wid + 1] = a1 + clfb[1];
    }
}

extern "C" void kernel_launch(void* const* d_in, const int* in_sizes, int n_in,
                              void* d_out, int out_size, void* d_ws, size_t ws_size,
                              hipStream_t stream) {
    const float* nodes = (const float*)d_in[0];
    const int*   edges = (const int*)d_in[1];
    const float* W     = (const float*)d_in[2];
    const float* b     = (const float*)d_in[3];
    const float* clfW  = (const float*)d_in[4];
    const float* clfb  = (const float*)d_in[5];
    float* out = (float*)d_out;

    const int N = N_NODES, E = N_EDGES;

    // workspace layout (16B-aligned blocks)
    float* X    = (float*)d_ws;              // N*128 fp32
    u16* Yhi    = (u16*)(X + (size_t)N * DIM);   // N*128 bf16 (swizzled)
    u16* Ylo    = Yhi + (size_t)N * DIM;
    u16* WhiT   = Ylo + (size_t)N * DIM;     // 3*128*128 (transposed+swizzled)
    u16* WloT   = WhiT + 3 * DIM * DIM;
    float* dinv = (float*)(WloT + 3 * DIM * DIM);  // N
    int* deg    = (int*)(dinv + N);
    int* off    = deg + N;
    int* cursor = off + N;
    int* csr    = cursor + N;                // N+E
    int* bsums  = csr + NE_TOT;              // 128

    const int nchunks = (N + 1023) / 1024;

    wsplit_kernel<<<(3 * DIM * DIM) / 256, 256, 0, stream>>>(W, WhiT, WloT);
    init_deg_kernel<<<(N + 255) / 256, 256, 0, stream>>>(deg, N);
    count_deg_kernel<<<(E + 255) / 256, 256, 0, stream>>>(edges, deg, E);
    scan1_kernel<<<nchunks, 256, 0, stream>>>(deg, off, bsums, N);
    scan2_kernel<<<1, 128, 0, stream>>>(bsums, nchunks);
    scan3_kernel<<<(N + 255) / 256, 256, 0, stream>>>(off, bsums, deg, cursor, dinv, N);
    fill_csr_kernel<<<(NE_TOT + 255) / 256, 256, 0, stream>>>(edges, cursor, csr);

    const int aggBlocks = (N + 3) / 4;
    const int gemmBlocks = (N + 127) / 128;

    aggregate_kernel<<<aggBlocks, 256, 0, stream>>>(nodes, Yhi, Ylo, off, csr, dinv, N);
    gemm_mfma_kernel<<<gemmBlocks, 512, 0, stream>>>(Yhi, Ylo, WhiT, WloT, b, X, N);

    aggregate_kernel<<<aggBlocks, 256, 0, stream>>>(X, Yhi, Ylo, off, csr, dinv, N);
    gemm_mfma_kernel<<<gemmBlocks, 512, 0, stream>>>(Yhi, Ylo, WhiT + DIM * DIM, WloT + DIM * DIM,
                                                     b + DIM, X, N);

    aggregate_kernel<<<aggBlocks, 256, 0, stream>>>(X, Yhi, Ylo, off, csr, dinv, N);
    gemm_mfma_kernel<<<gemmBlocks, 512, 0, stream>>>(Yhi, Ylo, WhiT + 2 * DIM * DIM, WloT + 2 * DIM * DIM,
                                                     b + 2 * DIM, X, N);

    classifier_kernel<<<aggBlocks, 256, 0, stream>>>(X, clfW, clfb, out, N);
}

// Round 11
// 453.219 us; speedup vs baseline: 1.3767x; 1.2320x over previous
//
#include <hip/hip_runtime.h>
#include <hip/hip_bf16.h>

#define N_NODES 100000
#define N_EDGES 640000
#define DIM 128
#define NE_TOT (N_NODES + N_EDGES)

typedef unsigned short u16;
typedef unsigned int u32;
typedef __attribute__((ext_vector_type(8))) short bf16x8;   // 8 bf16 bit-patterns (guide §3 convention)
typedef __attribute__((ext_vector_type(4))) float f32x4;
typedef __attribute__((ext_vector_type(8))) unsigned short us8;

__device__ __forceinline__ u16 f2bf(float f) {
    u32 u = __float_as_uint(f);
    u32 r = (u + 0x7fffu + ((u >> 16) & 1u)) >> 16;   // RNE
    return (u16)r;
}
__device__ __forceinline__ float bf2f(u16 h) { return __uint_as_float(((u32)h) << 16); }

__device__ __forceinline__ void gload16(const void* g, void* l) {
    __builtin_amdgcn_global_load_lds(
        (const __attribute__((address_space(1))) u32*)g,
        (__attribute__((address_space(3))) u32*)l, 16, 0, 0);
}

// ---------------- graph prep ----------------

__global__ void init_deg_kernel(int* deg, int n) {
    int i = blockIdx.x * blockDim.x + threadIdx.x;
    if (i < n) deg[i] = 1;  // self-loop
}

__global__ void count_deg_kernel(const int* __restrict__ edges, int* deg, int e) {
    int i = blockIdx.x * blockDim.x + threadIdx.x;
    if (i < e) atomicAdd(&deg[edges[N_EDGES + i]], 1);  // dst row
}

__global__ void scan1_kernel(const int* __restrict__ deg, int* off, int* bsums, int n) {
    __shared__ int lds[256];
    int t = threadIdx.x;
    int base = blockIdx.x * 1024 + t * 4;
    int v[4]; int s = 0;
#pragma unroll
    for (int j = 0; j < 4; j++) { int idx = base + j; v[j] = (idx < n) ? deg[idx] : 0; s += v[j]; }
    lds[t] = s; __syncthreads();
    for (int d = 1; d < 256; d <<= 1) {
        int x = 0;
        if (t >= d) x = lds[t - d];
        __syncthreads();
        if (t >= d) lds[t] += x;
        __syncthreads();
    }
    if (t == 255) bsums[blockIdx.x] = lds[255];
    int run = lds[t] - s;
#pragma unroll
    for (int j = 0; j < 4; j++) { int idx = base + j; if (idx < n) off[idx] = run; run += v[j]; }
}

__global__ void scan2_kernel(int* bsums, int nchunks) {
    __shared__ int lds[128];
    int t = threadIdx.x;
    int v = (t < nchunks) ? bsums[t] : 0;
    lds[t] = v; __syncthreads();
    for (int d = 1; d < 128; d <<= 1) {
        int x = 0;
        if (t >= d) x = lds[t - d];
        __syncthreads();
        if (t >= d) lds[t] += x;
        __syncthreads();
    }
    if (t < nchunks) bsums[t] = lds[t] - v;
}

__global__ void scan3_kernel(int* off, const int* __restrict__ bsums, const int* __restrict__ deg,
                             int* cursor, float* dinv, int n) {
    int i = blockIdx.x * blockDim.x + threadIdx.x;
    if (i < n) {
        int o = off[i] + bsums[i >> 10];
        off[i] = o;
        cursor[i] = o;
        dinv[i] = 1.0f / sqrtf((float)deg[i]);
    }
}

__global__ void fill_csr_kernel(const int* __restrict__ edges, int* cursor, int* csr) {
    int i = blockIdx.x * blockDim.x + threadIdx.x;
    if (i < N_NODES) {
        int p = atomicAdd(&cursor[i], 1);
        csr[p] = i;
    } else if (i < NE_TOT) {
        int e = i - N_NODES;
        int s = edges[e];
        int d = edges[N_EDGES + e];
        int p = atomicAdd(&cursor[d], 1);
        csr[p] = s;
    }
}

// ---------------- W prep: split fp32 W -> bf16 hi/lo, transposed [col][k], pre-swizzled ----------------
__global__ void wsplit_kernel(const float* __restrict__ W, u16* __restrict__ WhiT, u16* __restrict__ WloT) {
    int i = blockIdx.x * 256 + threadIdx.x;       // 0 .. 3*128*128-1
    int l = i >> 14; int r = i & 16383; int k = r >> 7; int c = r & 127;
    float w = W[i];                                // W[l][k][c]
    u16 h = f2bf(w);
    u16 lo = f2bf(w - bf2f(h));
    u32 inner = ((u32)(k * 2)) ^ (((u32)c & 7u) << 4);   // swizzled byte within 256B row
    size_t db = (size_t)l * 32768 + (size_t)c * 256 + inner;
    *(u16*)((char*)WhiT + db) = h;
    *(u16*)((char*)WloT + db) = lo;
}

// ---------------- aggregation: 4 nodes per wave (16-lane groups), 4 independent gather chains ----------------
// Per-element accumulation order over k is identical to the wave-per-node version -> bitwise-same Y.
__global__ void aggregate_kernel(const float* __restrict__ x, u16* __restrict__ yhi, u16* __restrict__ ylo,
                                 const int* __restrict__ off, const int* __restrict__ csr,
                                 const float* __restrict__ dinv, int n) {
    int gw = (blockIdx.x * blockDim.x + threadIdx.x) >> 6;   // global wave id
    int lane = threadIdx.x & 63;
    int grp = lane >> 4;                                     // node-group within wave
    int l4  = lane & 15;
    int node = gw * 4 + grp;
    if (node >= n) return;
    int start = off[node];
    int end = (node == n - 1) ? NE_TOT : off[node + 1];
    float a[8] = {0.f, 0.f, 0.f, 0.f, 0.f, 0.f, 0.f, 0.f};
    for (int k = start; k < end; k++) {
        int s = csr[k];
        float w = dinv[s];
        const float* row = x + (size_t)s * DIM + l4 * 8;
        float4 v0 = *reinterpret_cast<const float4*>(row);
        float4 v1 = *reinterpret_cast<const float4*>(row + 4);
        a[0] += v0.x * w; a[1] += v0.y * w; a[2] += v0.z * w; a[3] += v0.w * w;
        a[4] += v1.x * w; a[5] += v1.y * w; a[6] += v1.z * w; a[7] += v1.w * w;
    }
    float di = dinv[node];
    u16 h[8], lo[8];
#pragma unroll
    for (int j = 0; j < 8; j++) {
        float v = a[j] * di;
        h[j]  = f2bf(v);
        lo[j] = f2bf(v - bf2f(h[j]));
    }
    u32 inner = ((u32)(l4 * 16)) ^ (((u32)node & 7u) << 4);  // pre-swizzled 16B slot
    uint4 hv, lv;
    hv.x = (u32)h[0]  | ((u32)h[1]  << 16); hv.y = (u32)h[2]  | ((u32)h[3]  << 16);
    hv.z = (u32)h[4]  | ((u32)h[5]  << 16); hv.w = (u32)h[6]  | ((u32)h[7]  << 16);
    lv.x = (u32)lo[0] | ((u32)lo[1] << 16); lv.y = (u32)lo[2] | ((u32)lo[3] << 16);
    lv.z = (u32)lo[4] | ((u32)lo[5] << 16); lv.w = (u32)lo[6] | ((u32)lo[7] << 16);
    *reinterpret_cast<uint4*>((char*)yhi + (size_t)node * 256 + inner) = hv;
    *reinterpret_cast<uint4*>((char*)ylo + (size_t)node * 256 + inner) = lv;
}

// ---------------- split-bf16 MFMA GEMM: out = relu(Y @ W + b) ----------------
// block: 512 thr (8 waves = 4 row x 2 col), tile 128 rows x 128 cols, K=128 unrolled.
// LDS 64KB: Ah/Al [128][128] bf16 swizzled (Y tile only).
// B (W^T) fragments read DIRECT from global/L2: the staged LDS copy was byte-identical
// to the global array, so this is a pointer-base substitution (W is L2-resident, 782-block reuse).
// 3-product split GEMM: hi*hi + hi*lo + lo*hi (lo*lo term < 2^-18 rel, dropped).
__device__ __forceinline__ bf16x8 lds_frag(const char* base, int row, int kbyte) {
    int off = row * 256 + (kbyte ^ ((row & 7) << 4));
    return __builtin_bit_cast(bf16x8, *(const us8*)(base + off));
}

__global__ __launch_bounds__(512, 4) void gemm_mfma_kernel(
        const u16* __restrict__ Yhi, const u16* __restrict__ Ylo,
        const u16* __restrict__ WhiT, const u16* __restrict__ WloT,
        const float* __restrict__ bias, float* __restrict__ out, int M) {
    __shared__ char smem[65536];
    char* Ah = smem;
    char* Al = smem + 32768;
    const int t = threadIdx.x;
    const int lane = t & 63, w = t >> 6;
    const int rowbase = blockIdx.x * 128;

    // stage A (Y tile): each wave copies its 16-row slice (linear dest, src already swizzled)
#pragma unroll
    for (int it = 0; it < 4; it++) {
        int p = w * 4096 + it * 1024 + lane * 16;   // byte within 32KB tile
        int rl = p >> 8;
        int rg = rowbase + rl; rg = (rg < M) ? rg : (M - 1);
        int inner = p & 255;
        gload16((const char*)Yhi + (size_t)rg * 256 + inner, Ah + w * 4096 + it * 1024);
        gload16((const char*)Ylo + (size_t)rg * 256 + inner, Al + w * 4096 + it * 1024);
    }
    __syncthreads();

    const int wr = w >> 1, wc = w & 1;
    const int lr = lane & 15, kh = lane >> 4;
    f32x4 acc[2][4] = {};

#pragma unroll
    for (int ks = 0; ks < 4; ks++) {
        int kb = ks * 64 + kh * 16;
        bf16x8 ah[2], al[2], bh[4], bl[4];
#pragma unroll
        for (int ri = 0; ri < 2; ri++) {
            ah[ri] = lds_frag(Ah, wr * 32 + ri * 16 + lr, kb);
            al[ri] = lds_frag(Al, wr * 32 + ri * 16 + lr, kb);
        }
#pragma unroll
        for (int ci = 0; ci < 4; ci++) {
            int brow = wc * 64 + ci * 16 + lr;
            bh[ci] = lds_frag((const char*)WhiT, brow, kb);   // direct L2 read, same byte offsets
            bl[ci] = lds_frag((const char*)WloT, brow, kb);
        }
#pragma unroll
        for (int ri = 0; ri < 2; ri++)
#pragma unroll
            for (int ci = 0; ci < 4; ci++) {
                acc[ri][ci] = __builtin_amdgcn_mfma_f32_16x16x32_bf16(ah[ri], bh[ci], acc[ri][ci], 0, 0, 0);
                acc[ri][ci] = __builtin_amdgcn_mfma_f32_16x16x32_bf16(ah[ri], bl[ci], acc[ri][ci], 0, 0, 0);
                acc[ri][ci] = __builtin_amdgcn_mfma_f32_16x16x32_bf16(al[ri], bh[ci], acc[ri][ci], 0, 0, 0);
            }
    }

    // epilogue: C/D layout col=lane&15, row=(lane>>4)*4+reg  [m89-verified]
#pragma unroll
    for (int ri = 0; ri < 2; ri++)
#pragma unroll
        for (int ci = 0; ci < 4; ci++) {
            int col = wc * 64 + ci * 16 + lr;
            float bc = bias[col];
            int r0 = rowbase + wr * 32 + ri * 16 + kh * 4;
#pragma unroll
            for (int j = 0; j < 4; j++) {
                int r = r0 + j;
                if (r < M) out[(size_t)r * 128 + col] = fmaxf(acc[ri][ci][j] + bc, 0.f);
            }
        }
}

// ---------------- classifier ----------------
__global__ void classifier_kernel(const float* __restrict__ x, const float* __restrict__ clfW,
                                  const float* __restrict__ clfb, float* __restrict__ out, int n) {
    int wid = (blockIdx.x * blockDim.x + threadIdx.x) >> 6;
    int lane = threadIdx.x & 63;
    if (wid >= n) return;
    float w00 = clfW[2 * lane], w01 = clfW[2 * lane + 1];
    float w10 = clfW[2 * (lane + 64)], w11 = clfW[2 * (lane + 64) + 1];
    float x0 = x[(size_t)wid * DIM + lane];
    float x1 = x[(size_t)wid * DIM + lane + 64];
    float a0 = x0 * w00 + x1 * w10;
    float a1 = x0 * w01 + x1 * w11;
#pragma unroll
    for (int d = 32; d > 0; d >>= 1) {
        a0 += __shfl_down(a0, d);
        a1 += __shfl_down(a1, d);
    }
    if (lane == 0) {
        out[2 * wid]     = a0 + clfb[0];
        out[2 * wid + 1] = a1 + clfb[1];
    }
}

extern "C" void kernel_launch(void* const* d_in, const int* in_sizes, int n_in,
                              void* d_out, int out_size, void* d_ws, size_t ws_size,
                              hipStream_t stream) {
    const float* nodes = (const float*)d_in[0];
    const int*   edges = (const int*)d_in[1];
    const float* W     = (const float*)d_in[2];
    const float* b     = (const float*)d_in[3];
    const float* clfW  = (const float*)d_in[4];
    const float* clfb  = (const float*)d_in[5];
    float* out = (float*)d_out;

    const int N = N_NODES, E = N_EDGES;

    // workspace layout (16B-aligned blocks)
    float* X    = (float*)d_ws;              // N*128 fp32
    u16* Yhi    = (u16*)(X + (size_t)N * DIM);   // N*128 bf16 (swizzled)
    u16* Ylo    = Yhi + (size_t)N * DIM;
    u16* WhiT   = Ylo + (size_t)N * DIM;     // 3*128*128 (transposed+swizzled)
    u16* WloT   = WhiT + 3 * DIM * DIM;
    float* dinv = (float*)(WloT + 3 * DIM * DIM);  // N
    int* deg    = (int*)(dinv + N);
    int* off    = deg + N;
    int* cursor = off + N;
    int* csr    = cursor + N;                // N+E
    int* bsums  = csr + NE_TOT;              // 128

    const int nchunks = (N + 1023) / 1024;

    wsplit_kernel<<<(3 * DIM * DIM) / 256, 256, 0, stream>>>(W, WhiT, WloT);
    init_deg_kernel<<<(N + 255) / 256, 256, 0, stream>>>(deg, N);
    count_deg_kernel<<<(E + 255) / 256, 256, 0, stream>>>(edges, deg, E);
    scan1_kernel<<<nchunks, 256, 0, stream>>>(deg, off, bsums, N);
    scan2_kernel<<<1, 128, 0, stream>>>(bsums, nchunks);
    scan3_kernel<<<(N + 255) / 256, 256, 0, stream>>>(off, bsums, deg, cursor, dinv, N);
    fill_csr_kernel<<<(NE_TOT + 255) / 256, 256, 0, stream>>>(edges, cursor, csr);

    const int aggBlocks = (N + 15) / 16;          // 16 nodes per 256-thr block (4 waves x 4 nodes)
    const int gemmBlocks = (N + 127) / 128;

    aggregate_kernel<<<aggBlocks, 256, 0, stream>>>(nodes, Yhi, Ylo, off, csr, dinv, N);
    gemm_mfma_kernel<<<gemmBlocks, 512, 0, stream>>>(Yhi, Ylo, WhiT, WloT, b, X, N);

    aggregate_kernel<<<aggBlocks, 256, 0, stream>>>(X, Yhi, Ylo, off, csr, dinv, N);
    gemm_mfma_kernel<<<gemmBlocks, 512, 0, stream>>>(Yhi, Ylo, WhiT + DIM * DIM, WloT + DIM * DIM,
                                                     b + DIM, X, N);

    aggregate_kernel<<<aggBlocks, 256, 0, stream>>>(X, Yhi, Ylo, off, csr, dinv, N);
    gemm_mfma_kernel<<<gemmBlocks, 512, 0, stream>>>(Yhi, Ylo, WhiT + 2 * DIM * DIM, WloT + 2 * DIM * DIM,
                                                     b + 2 * DIM, X, N);

    classifier_kernel<<<(N + 3) / 4, 256, 0, stream>>>(X, clfW, clfb, out, N);
}